// Round 2
// baseline (4104.438 us; speedup 1.0000x reference)
//
#include <hip/hip_runtime.h>
#include <hip/hip_fp16.h>

// Problem constants (match reference)
#define B_      64
#define N_      256
#define M_      512
#define SIGMA_  1e-6f
#define RHO_    0.1f
#define ALPHA_  1.6f
#define BETA_   (-0.6f)   // 1 - ALPHA
#define ITERS_  200

#if defined(__has_builtin)
#if __has_builtin(__builtin_amdgcn_fdot2)
#define HAVE_FDOT2 1
#endif
#endif

typedef _Float16 h2_t __attribute__((ext_vector_type(2)));

__device__ __forceinline__ float fdot2f(__half2 a, __half2 b, float c) {
#ifdef HAVE_FDOT2
    return __builtin_amdgcn_fdot2(__builtin_bit_cast(h2_t, a),
                                  __builtin_bit_cast(h2_t, b), c, false);
#else
    return c + __low2float(a) * __low2float(b) + __high2float(a) * __high2float(b);
#endif
}

__device__ __forceinline__ float fdot2u(unsigned int a, unsigned int b, float c) {
    return fdot2f(__builtin_bit_cast(__half2, a), __builtin_bit_cast(__half2, b), c);
}

// ---------------------------------------------------------------------------
// Generic batched tiled GEMM:  C = alpha * op(A)*op(B) + beta * D
// 64x64 tile, BK=16, 256 threads, 4x4 per thread. All dims multiples of 64.
// A may be f16 (Ah) when tA==0. Output f32 (Cf) or f16 (Ch, optionally
// pair-packed along rows: Gp[m/2][n] = (C[m][n], C[m+1][n]) as __half2).
// When packPairs && Gdr: also writes f32 residual of the diagonal
// (Gdr[i] = C[i][i] - (float)f16(C[i][i])) for solver-side compensation.
// ---------------------------------------------------------------------------
__global__ __launch_bounds__(256) void gemm_bt(
    const float* __restrict__ Af, const __half* __restrict__ Ah, int lda, long long sA, int tA,
    const float* __restrict__ Bf, int ldb, long long sB, int tB,
    const float* __restrict__ Dp, int ldd, long long sD,
    float* __restrict__ Cf, __half* __restrict__ Ch, int ldc, long long sC,
    float alpha, float beta, int Mx, int Nx, int Kx, int packPairs,
    float* __restrict__ Gdr, long long sGdr)
{
    __shared__ float as_[16][68];
    __shared__ float bs_[16][68];

    const int tid = threadIdx.x;
    const int b   = blockIdx.z;
    const int i0  = blockIdx.y * 64;   // row (M) tile
    const int j0  = blockIdx.x * 64;   // col (N) tile

    if (Af) Af += (size_t)b * sA;
    if (Ah) Ah += (size_t)b * sA;
    Bf += (size_t)b * sB;
    if (Dp) Dp += (size_t)b * sD;
    if (Cf) Cf += (size_t)b * sC;
    if (Ch) Ch += (size_t)b * sC;
    if (Gdr) Gdr += (size_t)b * sGdr;

    const int ty = tid >> 4;      // 0..15 row group
    const int tx = tid & 15;      // 0..15 col group

    float acc[4][4] = {};

    #pragma unroll 1
    for (int k0 = 0; k0 < Kx; k0 += 16) {
        // ---- stage A tile: as_[k][i] = Aop[i0+i][k0+k]
        if (tA) {
            const int kk = tid >> 4, i4 = (tid & 15) << 2;
            float4 v = *(const float4*)(Af + (size_t)(k0 + kk) * lda + i0 + i4);
            *(float4*)&as_[kk][i4] = v;
        } else {
            const int ii = tid >> 2, k4 = (tid & 3) << 2;
            if (Ah) {
                const __half2* hp = (const __half2*)(Ah + (size_t)(i0 + ii) * lda + k0 + k4);
                __half2 h0 = hp[0], h1 = hp[1];
                as_[k4 + 0][ii] = __low2float(h0);
                as_[k4 + 1][ii] = __high2float(h0);
                as_[k4 + 2][ii] = __low2float(h1);
                as_[k4 + 3][ii] = __high2float(h1);
            } else {
                float4 v = *(const float4*)(Af + (size_t)(i0 + ii) * lda + k0 + k4);
                as_[k4 + 0][ii] = v.x; as_[k4 + 1][ii] = v.y;
                as_[k4 + 2][ii] = v.z; as_[k4 + 3][ii] = v.w;
            }
        }
        // ---- stage B tile: bs_[k][j] = Bop[k0+k][j0+j]
        if (tB) {
            const int jj = tid >> 2, k4 = (tid & 3) << 2;
            float4 v = *(const float4*)(Bf + (size_t)(j0 + jj) * ldb + k0 + k4);
            bs_[k4 + 0][jj] = v.x; bs_[k4 + 1][jj] = v.y;
            bs_[k4 + 2][jj] = v.z; bs_[k4 + 3][jj] = v.w;
        } else {
            const int kk = tid >> 4, j4 = (tid & 15) << 2;
            float4 v = *(const float4*)(Bf + (size_t)(k0 + kk) * ldb + j0 + j4);
            *(float4*)&bs_[kk][j4] = v;
        }
        __syncthreads();

        #pragma unroll
        for (int kk = 0; kk < 16; kk++) {
            float4 av = *(float4*)&as_[kk][ty << 2];
            float4 bv = *(float4*)&bs_[kk][tx << 2];
            acc[0][0] += av.x * bv.x; acc[0][1] += av.x * bv.y;
            acc[0][2] += av.x * bv.z; acc[0][3] += av.x * bv.w;
            acc[1][0] += av.y * bv.x; acc[1][1] += av.y * bv.y;
            acc[1][2] += av.y * bv.z; acc[1][3] += av.y * bv.w;
            acc[2][0] += av.z * bv.x; acc[2][1] += av.z * bv.y;
            acc[2][2] += av.z * bv.z; acc[2][3] += av.z * bv.w;
            acc[3][0] += av.w * bv.x; acc[3][1] += av.w * bv.y;
            acc[3][2] += av.w * bv.z; acc[3][3] += av.w * bv.w;
        }
        __syncthreads();
    }

    // ---- epilogue
    if (Ch) {
        if (packPairs) {
            __half2* C2 = (__half2*)Ch;
            const int mrow = i0 + (ty << 2);
            #pragma unroll
            for (int p = 0; p < 2; p++) {
                #pragma unroll
                for (int jj = 0; jj < 4; jj++) {
                    const float v0 = alpha * acc[2 * p][jj];
                    const float v1 = alpha * acc[2 * p + 1][jj];
                    __half2 h = __floats2half2_rn(v0, v1);
                    C2[(size_t)((mrow >> 1) + p) * ldc + j0 + (tx << 2) + jj] = h;
                    if (Gdr) {
                        const int col = j0 + (tx << 2) + jj;
                        const int r0  = mrow + 2 * p;
                        if (col == r0)          Gdr[col] = v0 - __low2float(h);
                        else if (col == r0 + 1) Gdr[col] = v1 - __high2float(h);
                    }
                }
            }
        } else {
            #pragma unroll
            for (int ii = 0; ii < 4; ii++) {
                #pragma unroll
                for (int jj = 0; jj < 4; jj++) {
                    Ch[(size_t)(i0 + (ty << 2) + ii) * ldc + j0 + (tx << 2) + jj] =
                        __float2half_rn(alpha * acc[ii][jj]);
                }
            }
        }
    } else {
        #pragma unroll
        for (int ii = 0; ii < 4; ii++) {
            const int m = i0 + (ty << 2) + ii;
            const int n = j0 + (tx << 2);
            float4 v;
            v.x = alpha * acc[ii][0]; v.y = alpha * acc[ii][1];
            v.z = alpha * acc[ii][2]; v.w = alpha * acc[ii][3];
            if (Dp) {
                float4 d = *(const float4*)(Dp + (size_t)m * ldd + n);
                v.x += beta * d.x; v.y += beta * d.y;
                v.z += beta * d.z; v.w += beta * d.w;
            }
            *(float4*)(Cf + (size_t)m * ldc + n) = v;
        }
    }
}

// ---------------------------------------------------------------------------
// Mmat[b][i][i] += P[b][i] + sigma ; also zero the solver's barrier counters
// (device-coherent store so the solver's agent-scope atomics see it).
// ---------------------------------------------------------------------------
__global__ void add_diag(float* __restrict__ Mm, const float* __restrict__ P,
                         unsigned int* __restrict__ barcnt)
{
    const int b = blockIdx.x, t = threadIdx.x;
    Mm[(size_t)b * 65536 + (size_t)t * 257] += P[b * 256 + t] + SIGMA_;
    if (t == 0)
        __hip_atomic_store(&barcnt[b], 0u, __ATOMIC_RELAXED, __HIP_MEMORY_SCOPE_AGENT);
}

// ---------------------------------------------------------------------------
// In-place Gauss-Jordan inverse of a 128x128 SPD matrix, fully in LDS.
// ---------------------------------------------------------------------------
__device__ __forceinline__ int gja(int i, int j)
{
    return (i << 7) + ((((j >> 2) ^ (i & 31)) << 2) | (j & 3));
}

__global__ __launch_bounds__(256) void gj128(
    const float* __restrict__ src, int lsrc, long long ssrc,
    float* __restrict__ dst, int ldst, long long sdst)
{
    extern __shared__ float Msh[];            // 16384 floats = 64 KiB
    __shared__ float sRowS[128], sCol[128], sPiv[1];

    const int tid = threadIdx.x, b = blockIdx.x;
    src += (size_t)b * ssrc;
    dst += (size_t)b * sdst;

    for (int qd = 0; qd < 64; qd++) {
        const int idx = qd * 256 + tid;
        const int i = idx >> 7, j = idx & 127;
        Msh[gja(i, j)] = src[(size_t)i * lsrc + j];
    }
    __syncthreads();

    #pragma unroll 1
    for (int k = 0; k < 128; k++) {
        if (tid < 128) {
            const float p  = Msh[gja(k, k)];
            const float ip = 1.0f / p;
            sRowS[tid] = Msh[gja(k, tid)] * ip;
            if (tid == 0) sPiv[0] = ip;
        } else {
            const int i = tid - 128;
            sCol[i] = Msh[gja(i, k)];
        }
        __syncthreads();

        const float ip = sPiv[0];
        {
            const int i  = tid >> 1;
            const int jb0 = (tid & 1) << 4;
            const float ck = sCol[i];
            #pragma unroll
            for (int jv = 0; jv < 16; jv++) {
                const int jb = jb0 + jv;
                const int a  = (i << 7) + (((jb ^ (i & 31)) << 2));
                float4 v = *(float4*)&Msh[a];
                float4 r = *(float4*)&sRowS[jb << 2];
                v.x -= ck * r.x; v.y -= ck * r.y;
                v.z -= ck * r.z; v.w -= ck * r.w;
                *(float4*)&Msh[a] = v;
            }
        }
        __syncthreads();

        if (tid < 128) {
            Msh[gja(k, tid)] = (tid == k) ? ip : sRowS[tid];
        } else {
            const int i = tid - 128;
            if (i != k) Msh[gja(i, k)] = -sCol[i] * ip;
        }
        __syncthreads();
    }

    for (int qd = 0; qd < 64; qd++) {
        const int idx = qd * 256 + tid;
        const int i = idx >> 7, j = idx & 127;
        dst[(size_t)i * ldst + j] = Msh[gja(i, j)];
    }
}

// ---------------------------------------------------------------------------
// Minv off-diagonal blocks
// ---------------------------------------------------------------------------
__global__ void assemble_offdiag(float* __restrict__ Minv, const float* __restrict__ V)
{
    const int b = blockIdx.x, tid = threadIdx.x;
    const float* Vb = V + (size_t)b * 16384;
    float* Mb = Minv + (size_t)b * 65536;
    for (int qd = 0; qd < 64; qd++) {
        const int idx = qd * 256 + tid;
        const int i = idx >> 7, j = idx & 127;
        const float v = -Vb[idx];
        Mb[(size_t)(128 + i) * 256 + j] = v;
        Mb[(size_t)j * 256 + 128 + i]   = v;
    }
}

// ---------------------------------------------------------------------------
// c0 = -Minv q ; d0 = A c0
// ---------------------------------------------------------------------------
__global__ __launch_bounds__(512) void c0d0_kernel(
    const float* __restrict__ Minv, const float* __restrict__ q,
    const float* __restrict__ A, float* __restrict__ c0, float* __restrict__ d0)
{
    __shared__ float qs[256], c0s[256];
    const int b = blockIdx.x, tid = threadIdx.x;
    const float* Mb = Minv + (size_t)b * 65536;

    if (tid < 256) qs[tid] = q[b * 256 + tid];
    __syncthreads();
    if (tid < 256) {
        float acc = 0.f;
        for (int j = 0; j < 256; j++)
            acc += Mb[(size_t)j * 256 + tid] * qs[j];
        c0s[tid] = -acc;
        c0[b * 256 + tid] = -acc;
    }
    __syncthreads();

    const int wid = tid >> 6, lane = tid & 63;
    const float* Ab = A + (size_t)b * 131072;
    for (int m = wid; m < 512; m += 8) {
        float4 a4 = *(const float4*)(Ab + (size_t)m * 256 + (lane << 2));
        float4 c4 = *(const float4*)&c0s[lane << 2];
        float acc = a4.x * c4.x + a4.y * c4.y + a4.z * c4.z + a4.w * c4.w;
        for (int off = 32; off > 0; off >>= 1) acc += __shfl_down(acc, off, 64);
        if (lane == 0) d0[b * 512 + m] = acc;
    }
}

// ---------------------------------------------------------------------------
// 4-CU-per-batch ADMM solver. Grid = 256 blocks (batch = blk>>2, part = blk&3).
// Each block holds a 128-output-row slice of G in LDS (f16, XOR-swizzled) and
// runs 200 iterations; the full 512-vector r is exchanged each iteration via a
// device-coherent global buffer + a 4-block monotonic-counter barrier.
//
// Global G layout (pair-packed): Gp[jj][i] = (G[2jj][i], G[2jj+1][i]) as h2,
// jj in [0,256), i in [0,512). Block `part` stages i in [128*part, 128*part+128)
// for all jj (uses G symmetry: out_row i = sum_m G[m][i] r[m]).
// LDS: Gsh[i_local][ (cc ^ (i_local&63))*4 + (jj&3) ], cc = jj>>2 (b128 chunks).
// ---------------------------------------------------------------------------
__global__ __launch_bounds__(512, 1) void solver4(
    const unsigned int* __restrict__ Gp,   // h2-as-uint, [B][256][512]
    const float* __restrict__ Gdr,         // diag residual [B][512]
    const float* __restrict__ d0g,
    const float* __restrict__ lg, const float* __restrict__ ug,
    float* __restrict__ uout,
    unsigned int* __restrict__ rbuf,       // [B][2][256] h2-as-uint
    unsigned int* __restrict__ barcnt)     // [B]
{
    __shared__ unsigned int Gsh[32768];    // 128 KiB
    __shared__ unsigned int rp_sh[256];    // packed r, full batch

    const int tid = threadIdx.x;
    const int b   = blockIdx.x >> 2;
    const int p   = blockIdx.x & 3;

    // ---- stage G slice: global (coalesced dwordx4) -> LDS (swizzled b32)
    {
        const unsigned int* Gg = Gp + (size_t)b * 131072 + 128 * p;
        for (int pp = 0; pp < 16; pp++) {
            const int idx = pp * 512 + tid;        // 8192 uint4 total
            const int jj = idx >> 5;               // [0,256)
            const int i4 = (idx & 31) << 2;        // [0,128) step 4
            uint4 v = *(const uint4*)&Gg[(size_t)jj * 512 + i4];
            const int cc = jj >> 2, s = jj & 3;
            #pragma unroll
            for (int d = 0; d < 4; d++) {
                const int i = i4 + d;
                const unsigned int val = d == 0 ? v.x : d == 1 ? v.y : d == 2 ? v.z : v.w;
                Gsh[(i << 8) + (((cc ^ (i & 63)) << 2) | s)] = val;
            }
        }
    }

    // ---- per-row state (replicated across the 4 lanes of each quad)
    const int il = tid >> 2;          // local output row [0,128)
    const int c  = tid & 3;           // column-chunk selector
    const int gi = 128 * p + il;      // global output row

    const float d0v  = d0g[b * 512 + gi];
    const float lv   = lg[b * 512 + gi];
    const float uv   = ug[b * 512 + gi];
    const float gdrv = Gdr[b * 512 + gi];
    float z = 0.f, y = 0.f, uacc = 0.f;

    unsigned int* rslot[2] = { rbuf + ((size_t)b * 2 + 0) * 256,
                               rbuf + ((size_t)b * 2 + 1) * 256 };
    unsigned int* bar = barcnt + b;

    __syncthreads();   // Gsh ready

    #pragma unroll 1
    for (int it = 0; it < ITERS_; it++) {
        const int par = it & 1;

        // -- r = rho*z - y ; u accumulation ; pack own 128 rows -> global
        const float rv = RHO_ * z - y;
        uacc = BETA_ * uacc + ALPHA_ * rv;
        const float rv2 = __shfl_down(rv, 4);      // partner row (il+1)
        if ((tid & 7) == 0) {
            const unsigned int pk =
                __builtin_bit_cast(unsigned int, __floats2half2_rn(rv, rv2));
            __hip_atomic_store(&rslot[par][64 * p + (tid >> 3)], pk,
                               __ATOMIC_RELAXED, __HIP_MEMORY_SCOPE_AGENT);
        }
        __syncthreads();                           // drain stores (vmcnt) pre-fence

        // -- 4-block barrier (monotonic counter)
        if (tid == 0) {
            __threadfence();
            __hip_atomic_fetch_add(bar, 1u, __ATOMIC_ACQ_REL, __HIP_MEMORY_SCOPE_AGENT);
            const unsigned int target = 4u * (unsigned int)(it + 1);
            int guard = 0;
            while (__hip_atomic_load(bar, __ATOMIC_RELAXED, __HIP_MEMORY_SCOPE_AGENT)
                       < target && guard < (1 << 27)) {
                __builtin_amdgcn_s_sleep(2);
                guard++;
            }
            __threadfence();
        }
        __syncthreads();

        // -- fetch full r (coherent loads bypass stale L2)
        if (tid < 256)
            rp_sh[tid] = __hip_atomic_load(&rslot[par][tid],
                                           __ATOMIC_RELAXED, __HIP_MEMORY_SCOPE_AGENT);
        __syncthreads();

        // -- z_tilde row gi: partial over m-chunk c, fdot2 from LDS
        const unsigned int* gro = Gsh + (il << 8);
        float a0 = 0.f, a1 = 0.f, a2 = 0.f, a3 = 0.f;
        #pragma unroll
        for (int k = 0; k < 16; k++) {
            const int cc  = (c << 4) + k;
            const int ccp = cc ^ (il & 63);
            uint4 g = *(const uint4*)&gro[ccp << 2];
            uint4 r = *(const uint4*)&rp_sh[cc << 2];
            a0 = fdot2u(g.x, r.x, a0);
            a1 = fdot2u(g.y, r.y, a1);
            a2 = fdot2u(g.z, r.z, a2);
            a3 = fdot2u(g.w, r.w, a3);
        }
        float part = (a0 + a1) + (a2 + a3);
        part += __shfl_xor(part, 1);
        part += __shfl_xor(part, 2);

        // -- relax / clip / dual update (replicated across quad lanes)
        const float zt = d0v + part + gdrv * rv;
        const float zr = ALPHA_ * zt + (1.0f - ALPHA_) * z;
        const float w  = zr + y * (1.0f / RHO_);
        const float zn = fminf(fmaxf(w, lv), uv);
        y = RHO_ * (w - zn);
        z = zn;
    }

    if ((tid & 3) == 0) uout[b * 512 + gi] = uacc;
}

// ---------------------------------------------------------------------------
// x = c0 + Minv (A^T u)
// ---------------------------------------------------------------------------
__global__ __launch_bounds__(256) void finalx(
    const float* __restrict__ Minv, const float* __restrict__ c0,
    const float* __restrict__ uacc, const float* __restrict__ A,
    float* __restrict__ out)
{
    __shared__ float us2[512], t1s[256];
    const int b = blockIdx.x, tid = threadIdx.x;

    us2[tid]       = uacc[b * 512 + tid];
    us2[tid + 256] = uacc[b * 512 + 256 + tid];
    __syncthreads();

    const float* Ab = A + (size_t)b * 131072;
    float acc = 0.f;
    for (int m = 0; m < 512; m++)
        acc += Ab[(size_t)m * 256 + tid] * us2[m];
    t1s[tid] = acc;
    __syncthreads();

    const float* Mb = Minv + (size_t)b * 65536;
    float x = c0[b * 256 + tid];
    for (int j = 0; j < 256; j++)
        x += Mb[(size_t)j * 256 + tid] * t1s[j];
    out[b * 256 + tid] = x;
}

// ---------------------------------------------------------------------------
// Host launcher
// ---------------------------------------------------------------------------
extern "C" void kernel_launch(void* const* d_in, const int* in_sizes, int n_in,
                              void* d_out, int out_size, void* d_ws, size_t ws_size,
                              hipStream_t stream)
{
    (void)in_sizes; (void)n_in; (void)out_size; (void)ws_size;

    const float* P = (const float*)d_in[0];
    const float* q = (const float*)d_in[1];
    const float* A = (const float*)d_in[2];
    const float* l = (const float*)d_in[3];
    const float* u = (const float*)d_in[4];
    float* out = (float*)d_out;
    char* ws = (char*)d_ws;

    // Workspace layout:
    //   [0,16M)   Mmat (fp32)        -> later reused by F (f16)
    //   [16M,32M) Minv (fp32)
    //   [32M,48M) E,T,S,V (4 MiB ea) -> dead before G written
    //   [32M,64M) G (f16 pair-packed, 32 MiB) overlays dead E..V
    //   [64M, ..) c0 | d0 | ua | Gdr | rbuf | barcnt
    float*  Mmat = (float*)(ws);
    __half* Fh   = (__half*)(ws);
    float*  Minv = (float*)(ws + (16ull << 20));
    float*  E    = (float*)(ws + (32ull << 20));
    float*  T    = (float*)(ws + (36ull << 20));
    float*  S    = (float*)(ws + (40ull << 20));
    float*  V    = (float*)(ws + (44ull << 20));
    __half* G    = (__half*)(ws + (32ull << 20));
    char*   tail = ws + (64ull << 20);
    float*        c0     = (float*)(tail);                 //  64 KB
    float*        d0     = (float*)(tail + 65536);         // 128 KB
    float*        ua     = (float*)(tail + 196608);        // 128 KB
    float*        Gdr    = (float*)(tail + 327680);        // 128 KB
    unsigned int* rbuf   = (unsigned int*)(tail + 458752); // 128 KB
    unsigned int* barcnt = (unsigned int*)(tail + 589824); // 256 B

    (void)hipFuncSetAttribute(reinterpret_cast<const void*>(&gj128),
                              hipFuncAttributeMaxDynamicSharedMemorySize, 65536);

    // 1) Mmat = RHO * A^T A
    gemm_bt<<<dim3(4, 4, 64), 256, 0, stream>>>(
        A, nullptr, 256, 131072, 1,  A, 256, 131072, 0,
        nullptr, 0, 0,  Mmat, nullptr, 256, 65536,
        RHO_, 0.f, 256, 256, 512, 0, nullptr, 0);

    // 2) += diag(P) + sigma I ; zero barrier counters
    add_diag<<<64, 256, 0, stream>>>(Mmat, P, barcnt);

    // 3) E = inv(M11)
    gj128<<<64, 256, 65536, stream>>>(Mmat, 256, 65536, E, 128, 16384);

    // 4) T = M21 * E
    gemm_bt<<<dim3(2, 2, 64), 256, 0, stream>>>(
        Mmat + 128 * 256, nullptr, 256, 65536, 0,  E, 128, 16384, 0,
        nullptr, 0, 0,  T, nullptr, 128, 16384,
        1.f, 0.f, 128, 128, 128, 0, nullptr, 0);

    // 5) S = M22 - T * M12
    gemm_bt<<<dim3(2, 2, 64), 256, 0, stream>>>(
        T, nullptr, 128, 16384, 0,  Mmat + 128, 256, 65536, 0,
        Mmat + 128 * 256 + 128, 256, 65536,
        S, nullptr, 128, 16384,
        -1.f, 1.f, 128, 128, 128, 0, nullptr, 0);

    // 6) Minv22 = inv(S)
    gj128<<<64, 256, 65536, stream>>>(S, 128, 16384, Minv + 128 * 256 + 128, 256, 65536);

    // 7) V = Sinv * T
    gemm_bt<<<dim3(2, 2, 64), 256, 0, stream>>>(
        Minv + 128 * 256 + 128, nullptr, 256, 65536, 0,  T, 128, 16384, 0,
        nullptr, 0, 0,  V, nullptr, 128, 16384,
        1.f, 0.f, 128, 128, 128, 0, nullptr, 0);

    // 8) Minv11 = E + T^T * V
    gemm_bt<<<dim3(2, 2, 64), 256, 0, stream>>>(
        T, nullptr, 128, 16384, 1,  V, 128, 16384, 0,
        E, 128, 16384,
        Minv, nullptr, 256, 65536,
        1.f, 1.f, 128, 128, 128, 0, nullptr, 0);

    // 9) Minv off-diagonals
    assemble_offdiag<<<64, 256, 0, stream>>>(Minv, V);

    // 10) c0 = -Minv q ; d0 = A c0
    c0d0_kernel<<<64, 512, 0, stream>>>(Minv, q, A, c0, d0);

    // 11) F = A * Minv   (f16 flat output, reuses Mmat slot)
    gemm_bt<<<dim3(4, 8, 64), 256, 0, stream>>>(
        A, nullptr, 256, 131072, 0,  Minv, 256, 65536, 0,
        nullptr, 0, 0,  nullptr, Fh, 256, 131072,
        1.f, 0.f, 512, 256, 256, 0, nullptr, 0);

    // 12) G = F * A^T   (f16 pair-packed + f32 diag residual)
    gemm_bt<<<dim3(8, 8, 64), 256, 0, stream>>>(
        nullptr, Fh, 256, 131072, 0,  A, 256, 131072, 1,
        nullptr, 0, 0,  nullptr, G, 512, 262144,
        1.f, 0.f, 512, 512, 256, 1, Gdr, 512);

    // 13) 200 ADMM iterations, 4 CUs per batch, G LDS-resident
    solver4<<<256, 512, 0, stream>>>((const unsigned int*)G, Gdr, d0, l, u,
                                     ua, rbuf, barcnt);

    // 14) x = c0 + Minv A^T u
    finalx<<<64, 256, 0, stream>>>(Minv, c0, ua, A, out);
}

// Round 3
// 1623.640 us; speedup vs baseline: 2.5279x; 2.5279x over previous
//
#include <hip/hip_runtime.h>
#include <hip/hip_fp16.h>

// Problem constants (match reference)
#define B_      64
#define N_      256
#define M_      512
#define SIGMA_  1e-6f
#define RHO_    0.1f
#define ALPHA_  1.6f
#define BETA_   (-0.6f)   // 1 - ALPHA
#define ITERS_  200

#if defined(__has_builtin)
#if __has_builtin(__builtin_amdgcn_fdot2)
#define HAVE_FDOT2 1
#endif
#endif

typedef _Float16 h2_t __attribute__((ext_vector_type(2)));

__device__ __forceinline__ float fdot2f(__half2 a, __half2 b, float c) {
#ifdef HAVE_FDOT2
    return __builtin_amdgcn_fdot2(__builtin_bit_cast(h2_t, a),
                                  __builtin_bit_cast(h2_t, b), c, false);
#else
    return c + __low2float(a) * __low2float(b) + __high2float(a) * __high2float(b);
#endif
}

__device__ __forceinline__ float fdot2u(unsigned int a, unsigned int b, float c) {
    return fdot2f(__builtin_bit_cast(__half2, a), __builtin_bit_cast(__half2, b), c);
}

// ---------------------------------------------------------------------------
// Generic batched tiled GEMM:  C = alpha * op(A)*op(B) + beta * D
// 64x64 tile, BK=16, 256 threads, 4x4 per thread. All dims multiples of 64.
// A may be f16 (Ah) when tA==0. Output f32 (Cf) or f16 (Ch, optionally
// pair-packed along rows: Gp[m/2][n] = (C[m][n], C[m+1][n]) as __half2).
// When packPairs && Gdr: also writes f32 residual of the diagonal
// (Gdr[i] = C[i][i] - (float)f16(C[i][i])) for solver-side compensation.
// ---------------------------------------------------------------------------
__global__ __launch_bounds__(256) void gemm_bt(
    const float* __restrict__ Af, const __half* __restrict__ Ah, int lda, long long sA, int tA,
    const float* __restrict__ Bf, int ldb, long long sB, int tB,
    const float* __restrict__ Dp, int ldd, long long sD,
    float* __restrict__ Cf, __half* __restrict__ Ch, int ldc, long long sC,
    float alpha, float beta, int Mx, int Nx, int Kx, int packPairs,
    float* __restrict__ Gdr, long long sGdr)
{
    __shared__ float as_[16][68];
    __shared__ float bs_[16][68];

    const int tid = threadIdx.x;
    const int b   = blockIdx.z;
    const int i0  = blockIdx.y * 64;   // row (M) tile
    const int j0  = blockIdx.x * 64;   // col (N) tile

    if (Af) Af += (size_t)b * sA;
    if (Ah) Ah += (size_t)b * sA;
    Bf += (size_t)b * sB;
    if (Dp) Dp += (size_t)b * sD;
    if (Cf) Cf += (size_t)b * sC;
    if (Ch) Ch += (size_t)b * sC;
    if (Gdr) Gdr += (size_t)b * sGdr;

    const int ty = tid >> 4;      // 0..15 row group
    const int tx = tid & 15;      // 0..15 col group

    float acc[4][4] = {};

    #pragma unroll 1
    for (int k0 = 0; k0 < Kx; k0 += 16) {
        // ---- stage A tile: as_[k][i] = Aop[i0+i][k0+k]
        if (tA) {
            const int kk = tid >> 4, i4 = (tid & 15) << 2;
            float4 v = *(const float4*)(Af + (size_t)(k0 + kk) * lda + i0 + i4);
            *(float4*)&as_[kk][i4] = v;
        } else {
            const int ii = tid >> 2, k4 = (tid & 3) << 2;
            if (Ah) {
                const __half2* hp = (const __half2*)(Ah + (size_t)(i0 + ii) * lda + k0 + k4);
                __half2 h0 = hp[0], h1 = hp[1];
                as_[k4 + 0][ii] = __low2float(h0);
                as_[k4 + 1][ii] = __high2float(h0);
                as_[k4 + 2][ii] = __low2float(h1);
                as_[k4 + 3][ii] = __high2float(h1);
            } else {
                float4 v = *(const float4*)(Af + (size_t)(i0 + ii) * lda + k0 + k4);
                as_[k4 + 0][ii] = v.x; as_[k4 + 1][ii] = v.y;
                as_[k4 + 2][ii] = v.z; as_[k4 + 3][ii] = v.w;
            }
        }
        // ---- stage B tile: bs_[k][j] = Bop[k0+k][j0+j]
        if (tB) {
            const int jj = tid >> 2, k4 = (tid & 3) << 2;
            float4 v = *(const float4*)(Bf + (size_t)(j0 + jj) * ldb + k0 + k4);
            bs_[k4 + 0][jj] = v.x; bs_[k4 + 1][jj] = v.y;
            bs_[k4 + 2][jj] = v.z; bs_[k4 + 3][jj] = v.w;
        } else {
            const int kk = tid >> 4, j4 = (tid & 15) << 2;
            float4 v = *(const float4*)(Bf + (size_t)(k0 + kk) * ldb + j0 + j4);
            *(float4*)&bs_[kk][j4] = v;
        }
        __syncthreads();

        #pragma unroll
        for (int kk = 0; kk < 16; kk++) {
            float4 av = *(float4*)&as_[kk][ty << 2];
            float4 bv = *(float4*)&bs_[kk][tx << 2];
            acc[0][0] += av.x * bv.x; acc[0][1] += av.x * bv.y;
            acc[0][2] += av.x * bv.z; acc[0][3] += av.x * bv.w;
            acc[1][0] += av.y * bv.x; acc[1][1] += av.y * bv.y;
            acc[1][2] += av.y * bv.z; acc[1][3] += av.y * bv.w;
            acc[2][0] += av.z * bv.x; acc[2][1] += av.z * bv.y;
            acc[2][2] += av.z * bv.z; acc[2][3] += av.z * bv.w;
            acc[3][0] += av.w * bv.x; acc[3][1] += av.w * bv.y;
            acc[3][2] += av.w * bv.z; acc[3][3] += av.w * bv.w;
        }
        __syncthreads();
    }

    // ---- epilogue
    if (Ch) {
        if (packPairs) {
            __half2* C2 = (__half2*)Ch;
            const int mrow = i0 + (ty << 2);
            #pragma unroll
            for (int p = 0; p < 2; p++) {
                #pragma unroll
                for (int jj = 0; jj < 4; jj++) {
                    const float v0 = alpha * acc[2 * p][jj];
                    const float v1 = alpha * acc[2 * p + 1][jj];
                    __half2 h = __floats2half2_rn(v0, v1);
                    C2[(size_t)((mrow >> 1) + p) * ldc + j0 + (tx << 2) + jj] = h;
                    if (Gdr) {
                        const int col = j0 + (tx << 2) + jj;
                        const int r0  = mrow + 2 * p;
                        if (col == r0)          Gdr[col] = v0 - __low2float(h);
                        else if (col == r0 + 1) Gdr[col] = v1 - __high2float(h);
                    }
                }
            }
        } else {
            #pragma unroll
            for (int ii = 0; ii < 4; ii++) {
                #pragma unroll
                for (int jj = 0; jj < 4; jj++) {
                    Ch[(size_t)(i0 + (ty << 2) + ii) * ldc + j0 + (tx << 2) + jj] =
                        __float2half_rn(alpha * acc[ii][jj]);
                }
            }
        }
    } else {
        #pragma unroll
        for (int ii = 0; ii < 4; ii++) {
            const int m = i0 + (ty << 2) + ii;
            const int n = j0 + (tx << 2);
            float4 v;
            v.x = alpha * acc[ii][0]; v.y = alpha * acc[ii][1];
            v.z = alpha * acc[ii][2]; v.w = alpha * acc[ii][3];
            if (Dp) {
                float4 d = *(const float4*)(Dp + (size_t)m * ldd + n);
                v.x += beta * d.x; v.y += beta * d.y;
                v.z += beta * d.z; v.w += beta * d.w;
            }
            *(float4*)(Cf + (size_t)m * ldc + n) = v;
        }
    }
}

// ---------------------------------------------------------------------------
// Mmat[b][i][i] += P[b][i] + sigma
// ---------------------------------------------------------------------------
__global__ void add_diag(float* __restrict__ Mm, const float* __restrict__ P)
{
    const int b = blockIdx.x, t = threadIdx.x;
    Mm[(size_t)b * 65536 + (size_t)t * 257] += P[b * 256 + t] + SIGMA_;
}

// ---------------------------------------------------------------------------
// In-place Gauss-Jordan inverse of a 128x128 SPD matrix, fully in LDS.
// ---------------------------------------------------------------------------
__device__ __forceinline__ int gja(int i, int j)
{
    return (i << 7) + ((((j >> 2) ^ (i & 31)) << 2) | (j & 3));
}

__global__ __launch_bounds__(256) void gj128(
    const float* __restrict__ src, int lsrc, long long ssrc,
    float* __restrict__ dst, int ldst, long long sdst)
{
    extern __shared__ float Msh[];            // 16384 floats = 64 KiB
    __shared__ float sRowS[128], sCol[128], sPiv[1];

    const int tid = threadIdx.x, b = blockIdx.x;
    src += (size_t)b * ssrc;
    dst += (size_t)b * sdst;

    for (int qd = 0; qd < 64; qd++) {
        const int idx = qd * 256 + tid;
        const int i = idx >> 7, j = idx & 127;
        Msh[gja(i, j)] = src[(size_t)i * lsrc + j];
    }
    __syncthreads();

    #pragma unroll 1
    for (int k = 0; k < 128; k++) {
        if (tid < 128) {
            const float p  = Msh[gja(k, k)];
            const float ip = 1.0f / p;
            sRowS[tid] = Msh[gja(k, tid)] * ip;
            if (tid == 0) sPiv[0] = ip;
        } else {
            const int i = tid - 128;
            sCol[i] = Msh[gja(i, k)];
        }
        __syncthreads();

        const float ip = sPiv[0];
        {
            const int i  = tid >> 1;
            const int jb0 = (tid & 1) << 4;
            const float ck = sCol[i];
            #pragma unroll
            for (int jv = 0; jv < 16; jv++) {
                const int jb = jb0 + jv;
                const int a  = (i << 7) + (((jb ^ (i & 31)) << 2));
                float4 v = *(float4*)&Msh[a];
                float4 r = *(float4*)&sRowS[jb << 2];
                v.x -= ck * r.x; v.y -= ck * r.y;
                v.z -= ck * r.z; v.w -= ck * r.w;
                *(float4*)&Msh[a] = v;
            }
        }
        __syncthreads();

        if (tid < 128) {
            Msh[gja(k, tid)] = (tid == k) ? ip : sRowS[tid];
        } else {
            const int i = tid - 128;
            if (i != k) Msh[gja(i, k)] = -sCol[i] * ip;
        }
        __syncthreads();
    }

    for (int qd = 0; qd < 64; qd++) {
        const int idx = qd * 256 + tid;
        const int i = idx >> 7, j = idx & 127;
        dst[(size_t)i * ldst + j] = Msh[gja(i, j)];
    }
}

// ---------------------------------------------------------------------------
// Minv off-diagonal blocks
// ---------------------------------------------------------------------------
__global__ void assemble_offdiag(float* __restrict__ Minv, const float* __restrict__ V)
{
    const int b = blockIdx.x, tid = threadIdx.x;
    const float* Vb = V + (size_t)b * 16384;
    float* Mb = Minv + (size_t)b * 65536;
    for (int qd = 0; qd < 64; qd++) {
        const int idx = qd * 256 + tid;
        const int i = idx >> 7, j = idx & 127;
        const float v = -Vb[idx];
        Mb[(size_t)(128 + i) * 256 + j] = v;
        Mb[(size_t)j * 256 + 128 + i]   = v;
    }
}

// ---------------------------------------------------------------------------
// c0 = -Minv q ; d0 = A c0
// ---------------------------------------------------------------------------
__global__ __launch_bounds__(512) void c0d0_kernel(
    const float* __restrict__ Minv, const float* __restrict__ q,
    const float* __restrict__ A, float* __restrict__ c0, float* __restrict__ d0)
{
    __shared__ float qs[256], c0s[256];
    const int b = blockIdx.x, tid = threadIdx.x;
    const float* Mb = Minv + (size_t)b * 65536;

    if (tid < 256) qs[tid] = q[b * 256 + tid];
    __syncthreads();
    if (tid < 256) {
        float acc = 0.f;
        for (int j = 0; j < 256; j++)
            acc += Mb[(size_t)j * 256 + tid] * qs[j];
        c0s[tid] = -acc;
        c0[b * 256 + tid] = -acc;
    }
    __syncthreads();

    const int wid = tid >> 6, lane = tid & 63;
    const float* Ab = A + (size_t)b * 131072;
    for (int m = wid; m < 512; m += 8) {
        float4 a4 = *(const float4*)(Ab + (size_t)m * 256 + (lane << 2));
        float4 c4 = *(const float4*)&c0s[lane << 2];
        float acc = a4.x * c4.x + a4.y * c4.y + a4.z * c4.z + a4.w * c4.w;
        for (int off = 32; off > 0; off >>= 1) acc += __shfl_down(acc, off, 64);
        if (lane == 0) d0[b * 512 + m] = acc;
    }
}

// ---------------------------------------------------------------------------
// ADMM solver v3: ONE block per batch item (no cross-block sync), 1024 threads.
// Thread (s = tid>>7 in [0,8), iq = tid&127): accumulates columns 4iq..4iq+3
// over jj-pair range [32s, 32s+32). jj in [0,64) staged in LDS (128 KiB,
// verbatim layout = conflict-free); jj in [64,256) read from L2 as coalesced
// uint4 (1 KiB/wave-instr) with double-buffered prefetch.
// Per-iter: 2 syncthreads, partial-sum reduction via part[8][512] in LDS.
// Threads tid<512 own column tid's (z,y,u) state and the clip/dual update.
// ---------------------------------------------------------------------------
__global__ __launch_bounds__(1024, 1) void solver_big(
    const unsigned int* __restrict__ Gp,   // h2-as-uint, [B][256][512]
    const float* __restrict__ Gdr,         // diag residual [B][512]
    const float* __restrict__ d0g,
    const float* __restrict__ lg, const float* __restrict__ ug,
    float* __restrict__ uout)
{
    __shared__ unsigned int Gsh[32768];    // jj 0..63 staged verbatim: 128 KiB
    __shared__ float part[8][512];         // 16 KiB partial sums
    __shared__ unsigned int rp_sh[256];    // packed r (h2)

    const int tid = threadIdx.x;
    const int b   = blockIdx.x;
    const int s   = tid >> 7;              // jj-octant [0,8)
    const int iq  = tid & 127;             // i-quad  [0,128)

    const unsigned int* Gb = Gp + (size_t)b * 131072;

    // ---- stage jj[0,64) x i[0,512) into LDS (verbatim copy, fully coalesced)
    {
        const uint4* src4 = (const uint4*)Gb;
        uint4* dst4 = (uint4*)Gsh;
        #pragma unroll
        for (int n = 0; n < 8; n++)
            dst4[n * 1024 + tid] = src4[n * 1024 + tid];
    }

    // ---- per-column state (threads tid<512 own column i=tid)
    float z = 0.f, y = 0.f, ua = 0.f, rv = 0.f;
    float d0v = 0.f, lv = 0.f, uv = 0.f, gdrv = 0.f;
    if (tid < 512) {
        d0v  = d0g[b * 512 + tid];
        lv   = lg[b * 512 + tid];
        uv   = ug[b * 512 + tid];
        gdrv = Gdr[b * 512 + tid];
    }

    // global-path base: element (jj=32s, i=4iq) as uint4; jj stride = 128 uint4
    const uint4* gb4 = (const uint4*)Gb + (size_t)(s << 5) * 128 + iq;
    const int fromLds = (s < 2);
    const unsigned int* lbase = Gsh + (s << 14) + (iq << 2);  // (32s*512 + 4iq)

    __syncthreads();

    #pragma unroll 1
    for (int it = 0; it < ITERS_; it++) {
        // ---- phase A: r update + pack (owners only; full waves, uniform)
        if (tid < 512) {
            rv = RHO_ * z - y;
            ua = BETA_ * ua + ALPHA_ * rv;
            const float rv2 = __shfl_xor(rv, 1);
            if (!(tid & 1))
                rp_sh[tid >> 1] =
                    __builtin_bit_cast(unsigned int, __floats2half2_rn(rv, rv2));
        }
        __syncthreads();   // S1: rp ready; prev part[] reads complete

        // ---- phase C: GEMV partials for columns 4iq..4iq+3 over jj [32s,32s+32)
        float a0 = 0.f, a1 = 0.f, a2 = 0.f, a3 = 0.f;
        if (fromLds) {
            #pragma unroll
            for (int k = 0; k < 32; k++) {
                uint4 g = *(const uint4*)(lbase + (k << 9));
                const unsigned int r = rp_sh[(s << 5) + k];
                a0 = fdot2u(g.x, r, a0); a1 = fdot2u(g.y, r, a1);
                a2 = fdot2u(g.z, r, a2); a3 = fdot2u(g.w, r, a3);
            }
        } else {
            uint4 g[2][4];
            #pragma unroll
            for (int d = 0; d < 4; d++) g[0][d] = gb4[(size_t)d * 128];
            #pragma unroll
            for (int c = 0; c < 8; c++) {
                const int cur = c & 1, nxt = cur ^ 1;
                if (c < 7) {
                    #pragma unroll
                    for (int d = 0; d < 4; d++)
                        g[nxt][d] = gb4[(size_t)(4 * (c + 1) + d) * 128];
                }
                #pragma unroll
                for (int d = 0; d < 4; d++) {
                    const unsigned int r = rp_sh[(s << 5) + 4 * c + d];
                    a0 = fdot2u(g[cur][d].x, r, a0);
                    a1 = fdot2u(g[cur][d].y, r, a1);
                    a2 = fdot2u(g[cur][d].z, r, a2);
                    a3 = fdot2u(g[cur][d].w, r, a3);
                }
            }
        }
        {
            float4 pv; pv.x = a0; pv.y = a1; pv.z = a2; pv.w = a3;
            *(float4*)&part[s][iq << 2] = pv;
        }
        __syncthreads();   // S2: parts ready

        // ---- phase E: reduce + relax/clip/dual (owners only)
        if (tid < 512) {
            float sum = 0.f;
            #pragma unroll
            for (int ss = 0; ss < 8; ss++) sum += part[ss][tid];
            const float zt = d0v + sum + gdrv * rv;
            const float zr = ALPHA_ * zt + (1.0f - ALPHA_) * z;
            const float w  = zr + y * (1.0f / RHO_);
            const float zn = fminf(fmaxf(w, lv), uv);
            y = RHO_ * (w - zn);
            z = zn;
        }
    }

    if (tid < 512) uout[b * 512 + tid] = ua;
}

// ---------------------------------------------------------------------------
// x = c0 + Minv (A^T u)
// ---------------------------------------------------------------------------
__global__ __launch_bounds__(256) void finalx(
    const float* __restrict__ Minv, const float* __restrict__ c0,
    const float* __restrict__ uacc, const float* __restrict__ A,
    float* __restrict__ out)
{
    __shared__ float us2[512], t1s[256];
    const int b = blockIdx.x, tid = threadIdx.x;

    us2[tid]       = uacc[b * 512 + tid];
    us2[tid + 256] = uacc[b * 512 + 256 + tid];
    __syncthreads();

    const float* Ab = A + (size_t)b * 131072;
    float acc = 0.f;
    for (int m = 0; m < 512; m++)
        acc += Ab[(size_t)m * 256 + tid] * us2[m];
    t1s[tid] = acc;
    __syncthreads();

    const float* Mb = Minv + (size_t)b * 65536;
    float x = c0[b * 256 + tid];
    for (int j = 0; j < 256; j++)
        x += Mb[(size_t)j * 256 + tid] * t1s[j];
    out[b * 256 + tid] = x;
}

// ---------------------------------------------------------------------------
// Host launcher
// ---------------------------------------------------------------------------
extern "C" void kernel_launch(void* const* d_in, const int* in_sizes, int n_in,
                              void* d_out, int out_size, void* d_ws, size_t ws_size,
                              hipStream_t stream)
{
    (void)in_sizes; (void)n_in; (void)out_size; (void)ws_size;

    const float* P = (const float*)d_in[0];
    const float* q = (const float*)d_in[1];
    const float* A = (const float*)d_in[2];
    const float* l = (const float*)d_in[3];
    const float* u = (const float*)d_in[4];
    float* out = (float*)d_out;
    char* ws = (char*)d_ws;

    // Workspace layout:
    //   [0,16M)   Mmat (fp32)        -> later reused by F (f16)
    //   [16M,32M) Minv (fp32)
    //   [32M,48M) E,T,S,V (4 MiB ea) -> dead before G written
    //   [32M,64M) G (f16 pair-packed, 32 MiB) overlays dead E..V
    //   [64M, ..) c0 | d0 | ua | Gdr
    float*  Mmat = (float*)(ws);
    __half* Fh   = (__half*)(ws);
    float*  Minv = (float*)(ws + (16ull << 20));
    float*  E    = (float*)(ws + (32ull << 20));
    float*  T    = (float*)(ws + (36ull << 20));
    float*  S    = (float*)(ws + (40ull << 20));
    float*  V    = (float*)(ws + (44ull << 20));
    __half* G    = (__half*)(ws + (32ull << 20));
    char*   tail = ws + (64ull << 20);
    float*  c0   = (float*)(tail);                 //  64 KB
    float*  d0   = (float*)(tail + 65536);         // 128 KB
    float*  ua   = (float*)(tail + 196608);        // 128 KB
    float*  Gdr  = (float*)(tail + 327680);        // 128 KB

    (void)hipFuncSetAttribute(reinterpret_cast<const void*>(&gj128),
                              hipFuncAttributeMaxDynamicSharedMemorySize, 65536);

    // 1) Mmat = RHO * A^T A
    gemm_bt<<<dim3(4, 4, 64), 256, 0, stream>>>(
        A, nullptr, 256, 131072, 1,  A, 256, 131072, 0,
        nullptr, 0, 0,  Mmat, nullptr, 256, 65536,
        RHO_, 0.f, 256, 256, 512, 0, nullptr, 0);

    // 2) += diag(P) + sigma I
    add_diag<<<64, 256, 0, stream>>>(Mmat, P);

    // 3) E = inv(M11)
    gj128<<<64, 256, 65536, stream>>>(Mmat, 256, 65536, E, 128, 16384);

    // 4) T = M21 * E
    gemm_bt<<<dim3(2, 2, 64), 256, 0, stream>>>(
        Mmat + 128 * 256, nullptr, 256, 65536, 0,  E, 128, 16384, 0,
        nullptr, 0, 0,  T, nullptr, 128, 16384,
        1.f, 0.f, 128, 128, 128, 0, nullptr, 0);

    // 5) S = M22 - T * M12
    gemm_bt<<<dim3(2, 2, 64), 256, 0, stream>>>(
        T, nullptr, 128, 16384, 0,  Mmat + 128, 256, 65536, 0,
        Mmat + 128 * 256 + 128, 256, 65536,
        S, nullptr, 128, 16384,
        -1.f, 1.f, 128, 128, 128, 0, nullptr, 0);

    // 6) Minv22 = inv(S)
    gj128<<<64, 256, 65536, stream>>>(S, 128, 16384, Minv + 128 * 256 + 128, 256, 65536);

    // 7) V = Sinv * T
    gemm_bt<<<dim3(2, 2, 64), 256, 0, stream>>>(
        Minv + 128 * 256 + 128, nullptr, 256, 65536, 0,  T, 128, 16384, 0,
        nullptr, 0, 0,  V, nullptr, 128, 16384,
        1.f, 0.f, 128, 128, 128, 0, nullptr, 0);

    // 8) Minv11 = E + T^T * V
    gemm_bt<<<dim3(2, 2, 64), 256, 0, stream>>>(
        T, nullptr, 128, 16384, 1,  V, 128, 16384, 0,
        E, 128, 16384,
        Minv, nullptr, 256, 65536,
        1.f, 1.f, 128, 128, 128, 0, nullptr, 0);

    // 9) Minv off-diagonals
    assemble_offdiag<<<64, 256, 0, stream>>>(Minv, V);

    // 10) c0 = -Minv q ; d0 = A c0
    c0d0_kernel<<<64, 512, 0, stream>>>(Minv, q, A, c0, d0);

    // 11) F = A * Minv   (f16 flat output, reuses Mmat slot)
    gemm_bt<<<dim3(4, 8, 64), 256, 0, stream>>>(
        A, nullptr, 256, 131072, 0,  Minv, 256, 65536, 0,
        nullptr, 0, 0,  nullptr, Fh, 256, 131072,
        1.f, 0.f, 512, 256, 256, 0, nullptr, 0);

    // 12) G = F * A^T   (f16 pair-packed + f32 diag residual)
    gemm_bt<<<dim3(8, 8, 64), 256, 0, stream>>>(
        nullptr, Fh, 256, 131072, 0,  A, 256, 131072, 1,
        nullptr, 0, 0,  nullptr, G, 512, 262144,
        1.f, 0.f, 512, 512, 256, 1, Gdr, 512);

    // 13) 200 ADMM iterations, one block per batch, partial-LDS G
    solver_big<<<64, 1024, 0, stream>>>((const unsigned int*)G, Gdr, d0, l, u, ua);

    // 14) x = c0 + Minv A^T u
    finalx<<<64, 256, 0, stream>>>(Minv, c0, ua, A, out);
}